// Round 14
// baseline (217.001 us; speedup 1.0000x reference)
//
#include <hip/hip_runtime.h>
#include <stdint.h>
#include <math.h>

#define NB 4
#define NN 4096
#define NF 256
#define ND 128
#define KVB 32
#define NR (NB * NN)
#define QKVE ((size_t)NR * ND)      // 2,097,152 elements

typedef __bf16 bf16x8 __attribute__((ext_vector_type(8)));
typedef __bf16 bf16x4v __attribute__((ext_vector_type(4)));
typedef float f32x4 __attribute__((ext_vector_type(4)));
typedef unsigned short u16x4 __attribute__((ext_vector_type(4)));

__device__ __forceinline__ unsigned short f2bf(float f) {
    union { float f; uint32_t u; } v; v.f = f;
    uint32_t r = (v.u + 0x7FFFu + ((v.u >> 16) & 1u)) >> 16;
    return (unsigned short)r;
}
__device__ __forceinline__ bf16x8 lds_read16(const unsigned short* base, int byte_off) {
    return *reinterpret_cast<const bf16x8*>(reinterpret_cast<const char*>(base) + byte_off);
}
__device__ __forceinline__ void gld_lds16(const void* g, void* l) {
    __builtin_amdgcn_global_load_lds(
        (const __attribute__((address_space(1))) void*)g,
        (__attribute__((address_space(3))) void*)l, 16, 0, 0);
}

// ------- Kernel 0+1 fused: pack adj bitmask (blocks 0..1023) + QKV proj -------
// (identical to round 13 — proven)
__global__ __launch_bounds__(256) void pack_proj(
    const int* __restrict__ adj, unsigned long long* __restrict__ pm64,
    const float* __restrict__ h,
    const float* __restrict__ Wq, const float* __restrict__ bq,
    const float* __restrict__ Wk, const float* __restrict__ bk,
    const float* __restrict__ Wv, const float* __restrict__ bv,
    unsigned short* __restrict__ qo, unsigned short* __restrict__ ko,
    unsigned short* __restrict__ vs, float qscale)
{
    __shared__ unsigned short h_lds[64 * 128];
    __shared__ unsigned short w_lds[128 * 128];

    const int tid = threadIdx.x;
    const int lane = tid & 63;

    if (blockIdx.x < 1024) {
        const int w = tid >> 6;
        const size_t base = ((size_t)blockIdx.x * 4 + w) * 256;
        for (int o = 0; o < 32; ++o) {
            const size_t wb = base + o * 8;
            int v[8];
#pragma unroll
            for (int u = 0; u < 8; ++u)
                v[u] = adj[(wb + u) * 64 + lane];
            unsigned long long m[8];
#pragma unroll
            for (int u = 0; u < 8; ++u)
                m[u] = __ballot(v[u] != 0);
            if (lane == 0) {
#pragma unroll
                for (int u = 0; u < 8; u += 2) {
                    ulonglong2 st; st.x = m[u]; st.y = m[u + 1];
                    *reinterpret_cast<ulonglong2*>(pm64 + wb + u) = st;
                }
            }
        }
        return;
    }

    const int idx = blockIdx.x - 1024;
    const int proj = idx >> 8;          // 0=Q,1=K,2=V
    const int R0 = (idx & 255) * 64;
    const int wv = tid >> 6;
    const int l15 = lane & 15;
    const int lhi = lane >> 4;

    const float* W    = proj == 0 ? Wq : (proj == 1 ? Wk : Wv);
    const float* bias = proj == 0 ? bq : (proj == 1 ? bk : bv);
    const float scale = proj == 0 ? qscale : 1.0f;

    f32x4 acc[8];
#pragma unroll
    for (int i = 0; i < 8; ++i) acc[i] = f32x4{0.f, 0.f, 0.f, 0.f};

    for (int kc = 0; kc < 2; ++kc) {
        const int c0 = kc * 128;
        __syncthreads();
#pragma unroll
        for (int p = 0; p < 8; ++p) {
            int i2 = p * 256 + tid;
            int row = i2 >> 5;
            int seg = i2 & 31;
            f32x4 hv = *reinterpret_cast<const f32x4*>(h + (size_t)(R0 + row) * NF + c0 + seg * 4);
            u16x4 hb;
            hb[0] = f2bf(hv[0]); hb[1] = f2bf(hv[1]); hb[2] = f2bf(hv[2]); hb[3] = f2bf(hv[3]);
            int byte = (row * 256 + seg * 8) ^ ((row & 7) << 4);
            *reinterpret_cast<u16x4*>(reinterpret_cast<char*>(h_lds) + byte) = hb;
        }
#pragma unroll
        for (int p = 0; p < 16; ++p) {
            int i2 = p * 256 + tid;
            int row = i2 >> 5;
            int seg = i2 & 31;
            f32x4 wv4 = *reinterpret_cast<const f32x4*>(W + (size_t)row * NF + c0 + seg * 4);
            u16x4 wb;
            wb[0] = f2bf(wv4[0]); wb[1] = f2bf(wv4[1]); wb[2] = f2bf(wv4[2]); wb[3] = f2bf(wv4[3]);
            int byte = (row * 256 + seg * 8) ^ ((row & 7) << 4);
            *reinterpret_cast<u16x4*>(reinterpret_cast<char*>(w_lds) + byte) = wb;
        }
        __syncthreads();
        const int arow = 16 * wv + l15;
#pragma unroll
        for (int ks = 0; ks < 4; ++ks) {
            int k = ks * 32 + 8 * lhi;
            bf16x8 a = lds_read16(h_lds, (arow * 256 + k * 2) ^ ((arow & 7) << 4));
#pragma unroll
            for (int cs = 0; cs < 8; ++cs) {
                int d = 16 * cs + l15;
                bf16x8 b = lds_read16(w_lds, (d * 256 + k * 2) ^ ((d & 7) << 4));
                acc[cs] = __builtin_amdgcn_mfma_f32_16x16x32_bf16(a, b, acc[cs], 0, 0, 0);
            }
        }
    }
    if (proj < 2) {
        unsigned short* out = proj == 0 ? qo : ko;
#pragma unroll
        for (int cs = 0; cs < 8; ++cs) {
            int d = 16 * cs + l15;
            float bb = bias[d];
#pragma unroll
            for (int j = 0; j < 4; ++j) {
                int row = R0 + 16 * wv + 4 * lhi + j;
                out[(size_t)row * ND + d] = f2bf((acc[cs][j] + bb) * scale);
            }
        }
    } else {
        const int bb_ = R0 >> 12;
        const int nb_ = (R0 & (NN - 1)) + 16 * wv + 4 * lhi;
        const int pt = nb_ >> 5;
        const int ch = (nb_ >> 3) & 3;
        const int mm0 = nb_ & 7;
#pragma unroll
        for (int cs = 0; cs < 8; ++cs) {
            int d = 16 * cs + l15;
            float bb = bias[d];
            u16x4 o;
#pragma unroll
            for (int j = 0; j < 4; ++j) o[j] = f2bf(acc[cs][j] + bb);
            size_t oidx = ((size_t)(bb_ * 128 + pt)) * 4096 + ch * 1024 + d * 8 + mm0;
            *reinterpret_cast<u16x4*>(vs + oidx) = o;
        }
    }
}

// -------- Kernel 2: LDS-staged flash attention (r13 structure) -----------------
// r14 change: grid 512->768 (nsplit=6, even pair-splits {22x4,20x2}) so
// 3 blocks/CU = 12 waves/CU = 3 waves/SIMD (r13's grid=512 capped at 2/SIMD).
// launch_bounds (256,3): reg cap 170 (est. live ~150 -- NOT the r4/r7 128 cap).
__global__ __launch_bounds__(256, 3) void attn(
    const unsigned short* __restrict__ Q,   // [B*N,128] bf16, scaled 1/(sqrt(128)*ln2)
    const unsigned short* __restrict__ K,   // [B*N,128] bf16 row-major
    const unsigned short* __restrict__ VS,  // tiled V (see proj)
    const unsigned int* __restrict__ pm,    // [B*N][128] packed adj words
    float* __restrict__ out,                // split-0 partial O (and final out)
    float* __restrict__ opart1,             // splits 1.. partial O (f32)
    float* __restrict__ ml,                 // [nsplit][NR][2] (m, l) log2-domain
    int nsplit)
{
    __shared__ unsigned short stA[8192];   // [0..4095]=K frags, [4096..8191]=V frags
    __shared__ unsigned short stB[8192];
    __shared__ unsigned short p_lds[4096]; // 4 waves x 2 groups x 1KB P^T tiles

    const int tid = threadIdx.x;
    const int lane = tid & 63;
    const int w = tid >> 6;
    const int l15 = lane & 15;
    const int lhi = lane >> 4;

    const int flat = blockIdx.x;
    const int x = flat & 7;
    const int rest = flat >> 3;
    const int qt = rest & 31;
    const int s3 = rest >> 5;
    const int combo = x + 8 * s3;           // b = combo&3 constant per XCD slot
    const int b = combo & 3;
    const int sp = combo >> 2;
    const int q0w = qt * 128 + w * 32;
    const size_t bN = (size_t)b * NN;

    // per-split tile range (even sizes so the step-2 loop works)
    int ptbase, ntl;
    if (nsplit == 6) {
        if (sp < 4) { ptbase = 22 * sp; ntl = 22; }
        else        { ptbase = 88 + 20 * (sp - 4); ntl = 20; }
    } else {
        ntl = 128 / nsplit; ptbase = sp * ntl;
    }

    const unsigned short* Kb = K + bN * ND;
    const unsigned short* Vbase = VS + (size_t)b * 128 * 4096;

    bf16x8 qf[2][4];
#pragma unroll
    for (int g = 0; g < 2; ++g)
#pragma unroll
        for (int ks = 0; ks < 4; ++ks)
            qf[g][ks] = *reinterpret_cast<const bf16x8*>(
                Q + (bN + q0w + g * 16 + l15) * ND + ks * 32 + 8 * lhi);

    const unsigned int* pmr0 = pm + (bN + (size_t)(q0w + l15)) * 128;
    const unsigned int* pmr1 = pm + (bN + (size_t)(q0w + 16 + l15)) * 128;

    f32x4 acc[2][8];
#pragma unroll
    for (int g = 0; g < 2; ++g)
#pragma unroll
        for (int i = 0; i < 8; ++i) acc[g][i] = f32x4{0.f, 0.f, 0.f, 0.f};
    float m_run[2] = {-INFINITY, -INFINITY};
    float l_part[2] = {0.f, 0.f};

    auto stage = [&](unsigned short* st, int pt) {
        const int m0 = pt * KVB;
#pragma unroll
        for (int i = 0; i < 4; ++i) {
            int c = w * 4 + i;                  // 0..15, wave-uniform
            if (c < 8) {                        // K frag block c = ms*4+ks
                int ms = c >> 2, ks = c & 3;
                const unsigned short* src = Kb
                    + (size_t)(m0 + ms * 16 + l15) * ND + ks * 32 + lhi * 8;
                gld_lds16(src, st + c * 512);
            } else {                            // V chunk (VS tile is the LDS image)
                int vi = c - 8;
                const unsigned short* src = Vbase + (size_t)pt * 4096 + vi * 512 + lane * 8;
                gld_lds16(src, st + 4096 + vi * 512);
            }
        }
    };

    auto compute = [&](const unsigned short* st, unsigned int mw0, unsigned int mw1) {
        bf16x8 kf[2][4];
#pragma unroll
        for (int ms = 0; ms < 2; ++ms)
#pragma unroll
            for (int ks = 0; ks < 4; ++ks)
                kf[ms][ks] = lds_read16(st, (ms * 4 + ks) * 1024 + lane * 16);

        f32x4 s[2][2];
#pragma unroll
        for (int g = 0; g < 2; ++g)
#pragma unroll
            for (int ms = 0; ms < 2; ++ms) s[g][ms] = f32x4{0.f, 0.f, 0.f, 0.f};
        __builtin_amdgcn_s_setprio(1);
#pragma unroll
        for (int g = 0; g < 2; ++g)
#pragma unroll
            for (int ms = 0; ms < 2; ++ms)
#pragma unroll
                for (int ks = 0; ks < 4; ++ks)
                    s[g][ms] = __builtin_amdgcn_mfma_f32_16x16x32_bf16(
                        kf[ms][ks], qf[g][ks], s[g][ms], 0, 0, 0);
        __builtin_amdgcn_s_setprio(0);

        bf16x8 vf[8];
#pragma unroll
        for (int ds = 0; ds < 8; ++ds)
            vf[ds] = lds_read16(st + 4096, lhi * 2048 + ds * 256 + l15 * 16);

        const unsigned int mw[2] = {mw0, mw1};
        float smaxl[2];
        float dmax = -INFINITY;
#pragma unroll
        for (int g = 0; g < 2; ++g) {
            unsigned int mwg = mw[g] >> (4 * lhi);
#pragma unroll
            for (int ms = 0; ms < 2; ++ms)
#pragma unroll
                for (int r = 0; r < 4; ++r)
                    if (!((mwg >> (16 * ms + r)) & 1u)) s[g][ms][r] = -1.0e30f;
            float mx = fmaxf(fmaxf(fmaxf(s[g][0][0], s[g][0][1]), fmaxf(s[g][0][2], s[g][0][3])),
                             fmaxf(fmaxf(s[g][1][0], s[g][1][1]), fmaxf(s[g][1][2], s[g][1][3])));
            smaxl[g] = mx;
            dmax = fmaxf(dmax, mx - m_run[g]);
        }
        if (!__all(dmax <= 8.0f)) {        // rare after warm-up
#pragma unroll
            for (int g = 0; g < 2; ++g) {
                float mx = smaxl[g];
                mx = fmaxf(mx, __shfl_xor(mx, 16, 64));
                mx = fmaxf(mx, __shfl_xor(mx, 32, 64));
                float mnew = fmaxf(m_run[g], mx);
                float c = exp2f(m_run[g] - mnew);
                m_run[g] = mnew;
                l_part[g] *= c;
#pragma unroll
                for (int ds = 0; ds < 8; ++ds) acc[g][ds] *= c;
            }
        }

#pragma unroll
        for (int g = 0; g < 2; ++g) {
            bf16x4v pbv[2];
#pragma unroll
            for (int ms = 0; ms < 2; ++ms)
#pragma unroll
                for (int r = 0; r < 4; ++r) {
                    float p = exp2f(s[g][ms][r] - m_run[g]);   // p <= 2^8
                    __bf16 pb = (__bf16)p;
                    l_part[g] += (float)pb;
                    pbv[ms][r] = pb;
                }
            const int base = (w * 2 + g) * 1024 + l15 * 64;
#pragma unroll
            for (int ms = 0; ms < 2; ++ms)
                *reinterpret_cast<bf16x4v*>(reinterpret_cast<char*>(p_lds)
                    + base + ms * 32 + lhi * 8) = pbv[ms];
            bf16x8 pa = lds_read16(p_lds, base + lhi * 16);
            __builtin_amdgcn_s_setprio(1);
#pragma unroll
            for (int ds = 0; ds < 8; ++ds)
                acc[g][ds] = __builtin_amdgcn_mfma_f32_16x16x32_bf16(
                    vf[ds], pa, acc[g][ds], 0, 0, 0);
            __builtin_amdgcn_s_setprio(0);
        }
    };

    // ---- pipeline: stage(t+1) issued before compute(t); sync per tile
    stage(stA, ptbase);
    __syncthreads();

    uint2 mk0 = *reinterpret_cast<const uint2*>(pmr0 + ptbase);
    uint2 mk1 = *reinterpret_cast<const uint2*>(pmr1 + ptbase);
    for (int t = 0; t < ntl; t += 2) {
        int tn = (t + 2 < ntl) ? t + 2 : t;
        uint2 nk0 = *reinterpret_cast<const uint2*>(pmr0 + ptbase + tn);
        uint2 nk1 = *reinterpret_cast<const uint2*>(pmr1 + ptbase + tn);

        stage(stB, ptbase + t + 1);
        compute(stA, mk0.x, mk1.x);
        __syncthreads();
        stage(stA, ptbase + (t + 2 < ntl ? t + 2 : ntl - 1));
        compute(stB, mk0.y, mk1.y);
        __syncthreads();

        mk0 = nk0; mk1 = nk1;
    }

    // ---- epilogue
#pragma unroll
    for (int g = 0; g < 2; ++g) {
        float rs = l_part[g];
        rs += __shfl_xor(rs, 16, 64);
        rs += __shfl_xor(rs, 32, 64);
        l_part[g] = rs;
    }

    float* op = (sp == 0) ? out : (opart1 + (size_t)(sp - 1) * NR * ND);
#pragma unroll
    for (int g = 0; g < 2; ++g) {
        const size_t rowbase = (bN + q0w + g * 16 + l15) * ND;
#pragma unroll
        for (int ds = 0; ds < 8; ++ds)
            *reinterpret_cast<f32x4*>(op + rowbase + 16 * ds + 4 * lhi) = acc[g][ds];
    }
    if (lhi == 0) {
#pragma unroll
        for (int g = 0; g < 2; ++g) {
            size_t gr = bN + q0w + g * 16 + l15;
            *reinterpret_cast<float2*>(ml + ((size_t)sp * NR + gr) * 2) =
                make_float2(m_run[g], l_part[g]);
        }
    }
}

// ---------------- Kernel 3: merge the KV-splits (m is log2-domain) -------------
__global__ __launch_bounds__(256) void merge_splits(
    float* __restrict__ out, const float* __restrict__ opart1,
    const float* __restrict__ ml, int nsplit)
{
    int idx = blockIdx.x * 256 + threadIdx.x;
    int row = idx >> 5;
    int d4 = (idx & 31) * 4;
    float mmax = ml[(size_t)row * 2];
    for (int sp = 1; sp < nsplit; ++sp)
        mmax = fmaxf(mmax, ml[((size_t)sp * NR + row) * 2]);
    f32x4 o0 = *reinterpret_cast<const f32x4*>(out + (size_t)row * ND + d4);
    float w0 = exp2f(ml[(size_t)row * 2] - mmax);
    float lsum = ml[(size_t)row * 2 + 1] * w0;
    f32x4 acc;
#pragma unroll
    for (int j = 0; j < 4; ++j) acc[j] = o0[j] * w0;
    for (int sp = 1; sp < nsplit; ++sp) {
        float m_s = ml[((size_t)sp * NR + row) * 2];
        float l_s = ml[((size_t)sp * NR + row) * 2 + 1];
        float ws_ = exp2f(m_s - mmax);
        f32x4 os = *reinterpret_cast<const f32x4*>(opart1 + ((size_t)(sp - 1) * NR + row) * ND + d4);
#pragma unroll
        for (int j = 0; j < 4; ++j) acc[j] += os[j] * ws_;
        lsum += l_s * ws_;
    }
    float inv = 1.0f / lsum;
    f32x4 r;
#pragma unroll
    for (int j = 0; j < 4; ++j) r[j] = acc[j] * inv;
    *reinterpret_cast<f32x4*>(out + (size_t)row * ND + d4) = r;
}

extern "C" void kernel_launch(void* const* d_in, const int* in_sizes, int n_in,
                              void* d_out, int out_size, void* d_ws, size_t ws_size,
                              hipStream_t stream) {
    const float* h  = (const float*)d_in[0];
    const int* adj  = (const int*)d_in[1];
    const float* Wq = (const float*)d_in[2];
    const float* bq = (const float*)d_in[3];
    const float* Wk = (const float*)d_in[4];
    const float* bk = (const float*)d_in[5];
    const float* Wv = (const float*)d_in[6];
    const float* bv = (const float*)d_in[7];
    float* out = (float*)d_out;

    unsigned short* qws  = (unsigned short*)d_ws;
    unsigned short* kws  = qws + QKVE;
    unsigned short* vsws = kws + QKVE;
    float* opart1 = (float*)(vsws + QKVE);

    const size_t pm_bytes = (size_t)NB * NN * (NN / 8);          // 8.39 MB
    // nsplit=6: qkv 12.6MB + 5 partials (42MB) + ml + pm
    const size_t need6 = 3 * QKVE * 2 + 5 * QKVE * 4 + 6 * (size_t)NR * 2 * 4 + pm_bytes;
    const size_t need4 = 3 * QKVE * 2 + 3 * QKVE * 4 + 4 * (size_t)NR * 2 * 4 + pm_bytes;
    const int nsplit = (ws_size >= need6) ? 6 : ((ws_size >= need4) ? 4 : 2);
    float* mlws = opart1 + (size_t)(nsplit - 1) * NR * ND;
    unsigned int* pmws = (unsigned int*)(mlws + (size_t)nsplit * NR * 2);

    // 1/(sqrt(128) * ln2): scores land in log2 units -> exp2 softmax
    const float qscale = (float)(0.08838834764831845 / 0.6931471805599453);

    pack_proj<<<dim3(1024 + 768), 256, 0, stream>>>(
        adj, (unsigned long long*)pmws,
        h, Wq, bq, Wk, bk, Wv, bv, qws, kws, vsws, qscale);
    attn<<<dim3(32 * 4 * nsplit), 256, 0, stream>>>(
        qws, kws, vsws, pmws, out, opart1, mlws, nsplit);
    merge_splits<<<dim3(NR * 32 / 256), 256, 0, stream>>>(out, opart1, mlws, nsplit);
}

// Round 15
// 159.739 us; speedup vs baseline: 1.3585x; 1.3585x over previous
//
#include <hip/hip_runtime.h>
#include <stdint.h>
#include <math.h>

#define NB 4
#define NN 4096
#define NF 256
#define ND 128
#define KVB 32
#define NR (NB * NN)
#define QKVE ((size_t)NR * ND)      // 2,097,152 elements

typedef __bf16 bf16x8 __attribute__((ext_vector_type(8)));
typedef __bf16 bf16x4v __attribute__((ext_vector_type(4)));
typedef float f32x4 __attribute__((ext_vector_type(4)));
typedef unsigned short u16x4 __attribute__((ext_vector_type(4)));

__device__ __forceinline__ unsigned short f2bf(float f) {
    union { float f; uint32_t u; } v; v.f = f;
    uint32_t r = (v.u + 0x7FFFu + ((v.u >> 16) & 1u)) >> 16;
    return (unsigned short)r;
}
__device__ __forceinline__ bf16x8 lds_read16(const unsigned short* base, int byte_off) {
    return *reinterpret_cast<const bf16x8*>(reinterpret_cast<const char*>(base) + byte_off);
}
__device__ __forceinline__ void gld_lds16(const void* g, void* l) {
    __builtin_amdgcn_global_load_lds(
        (const __attribute__((address_space(1))) void*)g,
        (__attribute__((address_space(3))) void*)l, 16, 0, 0);
}

// ------- Kernel 0+1 fused: pack adj bitmask (blocks 0..1023) + QKV proj -------
// (identical to round 13 — proven)
__global__ __launch_bounds__(256) void pack_proj(
    const int* __restrict__ adj, unsigned long long* __restrict__ pm64,
    const float* __restrict__ h,
    const float* __restrict__ Wq, const float* __restrict__ bq,
    const float* __restrict__ Wk, const float* __restrict__ bk,
    const float* __restrict__ Wv, const float* __restrict__ bv,
    unsigned short* __restrict__ qo, unsigned short* __restrict__ ko,
    unsigned short* __restrict__ vs, float qscale)
{
    __shared__ unsigned short h_lds[64 * 128];
    __shared__ unsigned short w_lds[128 * 128];

    const int tid = threadIdx.x;
    const int lane = tid & 63;

    if (blockIdx.x < 1024) {
        const int w = tid >> 6;
        const size_t base = ((size_t)blockIdx.x * 4 + w) * 256;
        for (int o = 0; o < 32; ++o) {
            const size_t wb = base + o * 8;
            int v[8];
#pragma unroll
            for (int u = 0; u < 8; ++u)
                v[u] = adj[(wb + u) * 64 + lane];
            unsigned long long m[8];
#pragma unroll
            for (int u = 0; u < 8; ++u)
                m[u] = __ballot(v[u] != 0);
            if (lane == 0) {
#pragma unroll
                for (int u = 0; u < 8; u += 2) {
                    ulonglong2 st; st.x = m[u]; st.y = m[u + 1];
                    *reinterpret_cast<ulonglong2*>(pm64 + wb + u) = st;
                }
            }
        }
        return;
    }

    const int idx = blockIdx.x - 1024;
    const int proj = idx >> 8;          // 0=Q,1=K,2=V
    const int R0 = (idx & 255) * 64;
    const int wv = tid >> 6;
    const int l15 = lane & 15;
    const int lhi = lane >> 4;

    const float* W    = proj == 0 ? Wq : (proj == 1 ? Wk : Wv);
    const float* bias = proj == 0 ? bq : (proj == 1 ? bk : bv);
    const float scale = proj == 0 ? qscale : 1.0f;

    f32x4 acc[8];
#pragma unroll
    for (int i = 0; i < 8; ++i) acc[i] = f32x4{0.f, 0.f, 0.f, 0.f};

    for (int kc = 0; kc < 2; ++kc) {
        const int c0 = kc * 128;
        __syncthreads();
#pragma unroll
        for (int p = 0; p < 8; ++p) {
            int i2 = p * 256 + tid;
            int row = i2 >> 5;
            int seg = i2 & 31;
            f32x4 hv = *reinterpret_cast<const f32x4*>(h + (size_t)(R0 + row) * NF + c0 + seg * 4);
            u16x4 hb;
            hb[0] = f2bf(hv[0]); hb[1] = f2bf(hv[1]); hb[2] = f2bf(hv[2]); hb[3] = f2bf(hv[3]);
            int byte = (row * 256 + seg * 8) ^ ((row & 7) << 4);
            *reinterpret_cast<u16x4*>(reinterpret_cast<char*>(h_lds) + byte) = hb;
        }
#pragma unroll
        for (int p = 0; p < 16; ++p) {
            int i2 = p * 256 + tid;
            int row = i2 >> 5;
            int seg = i2 & 31;
            f32x4 wv4 = *reinterpret_cast<const f32x4*>(W + (size_t)row * NF + c0 + seg * 4);
            u16x4 wb;
            wb[0] = f2bf(wv4[0]); wb[1] = f2bf(wv4[1]); wb[2] = f2bf(wv4[2]); wb[3] = f2bf(wv4[3]);
            int byte = (row * 256 + seg * 8) ^ ((row & 7) << 4);
            *reinterpret_cast<u16x4*>(reinterpret_cast<char*>(w_lds) + byte) = wb;
        }
        __syncthreads();
        const int arow = 16 * wv + l15;
#pragma unroll
        for (int ks = 0; ks < 4; ++ks) {
            int k = ks * 32 + 8 * lhi;
            bf16x8 a = lds_read16(h_lds, (arow * 256 + k * 2) ^ ((arow & 7) << 4));
#pragma unroll
            for (int cs = 0; cs < 8; ++cs) {
                int d = 16 * cs + l15;
                bf16x8 b = lds_read16(w_lds, (d * 256 + k * 2) ^ ((d & 7) << 4));
                acc[cs] = __builtin_amdgcn_mfma_f32_16x16x32_bf16(a, b, acc[cs], 0, 0, 0);
            }
        }
    }
    if (proj < 2) {
        unsigned short* out = proj == 0 ? qo : ko;
#pragma unroll
        for (int cs = 0; cs < 8; ++cs) {
            int d = 16 * cs + l15;
            float bb = bias[d];
#pragma unroll
            for (int j = 0; j < 4; ++j) {
                int row = R0 + 16 * wv + 4 * lhi + j;
                out[(size_t)row * ND + d] = f2bf((acc[cs][j] + bb) * scale);
            }
        }
    } else {
        const int bb_ = R0 >> 12;
        const int nb_ = (R0 & (NN - 1)) + 16 * wv + 4 * lhi;
        const int pt = nb_ >> 5;
        const int ch = (nb_ >> 3) & 3;
        const int mm0 = nb_ & 7;
#pragma unroll
        for (int cs = 0; cs < 8; ++cs) {
            int d = 16 * cs + l15;
            float bb = bias[d];
            u16x4 o;
#pragma unroll
            for (int j = 0; j < 4; ++j) o[j] = f2bf(acc[cs][j] + bb);
            size_t oidx = ((size_t)(bb_ * 128 + pt)) * 4096 + ch * 1024 + d * 8 + mm0;
            *reinterpret_cast<u16x4*>(vs + oidx) = o;
        }
    }
}

// -------- Kernel 2: LDS-staged flash attention, counted-vmcnt pipeline ---------
// r15 change vs r13: __syncthreads (implicit vmcnt(0) drain — serialized
// stage latency per tile) -> raw s_barrier + counted s_waitcnt vmcnt(6).
// Per body each wave issues exactly 6 VMEM ops (4 stage + 2 mask), so
// vmcnt(6) drains the PREVIOUS body's ops while this body's stay in flight
// across both barriers (T3/T4 minimum; proven in rounds 2-3).
// launch_bounds (256,2) — (256,3)/(256,4) spilled in r4/r7/r14.
__global__ __launch_bounds__(256, 2) void attn(
    const unsigned short* __restrict__ Q,   // [B*N,128] bf16, scaled 1/(sqrt(128)*ln2)
    const unsigned short* __restrict__ K,   // [B*N,128] bf16 row-major
    const unsigned short* __restrict__ VS,  // tiled V (see proj)
    const unsigned int* __restrict__ pm,    // [B*N][128] packed adj words
    float* __restrict__ out,                // split-0 partial O (and final out)
    float* __restrict__ opart1,             // splits 1.. partial O (f32)
    float* __restrict__ ml,                 // [nsplit][NR][2] (m, l) log2-domain
    int ntl)                                // tiles per split (32 or 64)
{
    __shared__ unsigned short stA[8192];   // [0..4095]=K frags, [4096..8191]=V frags
    __shared__ unsigned short stB[8192];
    __shared__ unsigned short p_lds[4096]; // 4 waves x 2 groups x 1KB P^T tiles

    const int tid = threadIdx.x;
    const int lane = tid & 63;
    const int w = tid >> 6;
    const int l15 = lane & 15;
    const int lhi = lane >> 4;

    const int flat = blockIdx.x;
    const int x = flat & 7;
    const int rest = flat >> 3;
    const int qt = rest & 31;
    const int s2 = rest >> 5;
    const int combo = x + 8 * s2;
    const int b = combo & 3;
    const int sp = combo >> 2;
    const int q0w = qt * 128 + w * 32;
    const size_t bN = (size_t)b * NN;
    const int ptbase = sp * ntl;

    const unsigned short* Kb = K + bN * ND;
    const unsigned short* Vbase = VS + (size_t)b * 128 * 4096;

    bf16x8 qf[2][4];
#pragma unroll
    for (int g = 0; g < 2; ++g)
#pragma unroll
        for (int ks = 0; ks < 4; ++ks)
            qf[g][ks] = *reinterpret_cast<const bf16x8*>(
                Q + (bN + q0w + g * 16 + l15) * ND + ks * 32 + 8 * lhi);

    const unsigned int* pmr0 = pm + (bN + (size_t)(q0w + l15)) * 128;
    const unsigned int* pmr1 = pm + (bN + (size_t)(q0w + 16 + l15)) * 128;

    f32x4 acc[2][8];
#pragma unroll
    for (int g = 0; g < 2; ++g)
#pragma unroll
        for (int i = 0; i < 8; ++i) acc[g][i] = f32x4{0.f, 0.f, 0.f, 0.f};
    float m_run[2] = {-INFINITY, -INFINITY};
    float l_part[2] = {0.f, 0.f};

    auto stage = [&](unsigned short* st, int pt) {
        const int m0 = pt * KVB;
#pragma unroll
        for (int i = 0; i < 4; ++i) {
            int c = w * 4 + i;                  // 0..15, wave-uniform
            if (c < 8) {                        // K frag block c = ms*4+ks
                int ms = c >> 2, ks = c & 3;
                const unsigned short* src = Kb
                    + (size_t)(m0 + ms * 16 + l15) * ND + ks * 32 + lhi * 8;
                gld_lds16(src, st + c * 512);
            } else {                            // V chunk (VS tile is the LDS image)
                int vi = c - 8;
                const unsigned short* src = Vbase + (size_t)pt * 4096 + vi * 512 + lane * 8;
                gld_lds16(src, st + 4096 + vi * 512);
            }
        }
    };

    auto compute = [&](const unsigned short* st, unsigned int mw0, unsigned int mw1) {
        bf16x8 kf[2][4];
#pragma unroll
        for (int ms = 0; ms < 2; ++ms)
#pragma unroll
            for (int ks = 0; ks < 4; ++ks)
                kf[ms][ks] = lds_read16(st, (ms * 4 + ks) * 1024 + lane * 16);

        f32x4 s[2][2];
#pragma unroll
        for (int g = 0; g < 2; ++g)
#pragma unroll
            for (int ms = 0; ms < 2; ++ms) s[g][ms] = f32x4{0.f, 0.f, 0.f, 0.f};
        __builtin_amdgcn_s_setprio(1);
#pragma unroll
        for (int g = 0; g < 2; ++g)
#pragma unroll
            for (int ms = 0; ms < 2; ++ms)
#pragma unroll
                for (int ks = 0; ks < 4; ++ks)
                    s[g][ms] = __builtin_amdgcn_mfma_f32_16x16x32_bf16(
                        kf[ms][ks], qf[g][ks], s[g][ms], 0, 0, 0);
        __builtin_amdgcn_s_setprio(0);

        bf16x8 vf[8];
#pragma unroll
        for (int ds = 0; ds < 8; ++ds)
            vf[ds] = lds_read16(st + 4096, lhi * 2048 + ds * 256 + l15 * 16);

        const unsigned int mw[2] = {mw0, mw1};
        float smaxl[2];
        float dmax = -INFINITY;
#pragma unroll
        for (int g = 0; g < 2; ++g) {
            unsigned int mwg = mw[g] >> (4 * lhi);
#pragma unroll
            for (int ms = 0; ms < 2; ++ms)
#pragma unroll
                for (int r = 0; r < 4; ++r)
                    if (!((mwg >> (16 * ms + r)) & 1u)) s[g][ms][r] = -1.0e30f;
            float mx = fmaxf(fmaxf(fmaxf(s[g][0][0], s[g][0][1]), fmaxf(s[g][0][2], s[g][0][3])),
                             fmaxf(fmaxf(s[g][1][0], s[g][1][1]), fmaxf(s[g][1][2], s[g][1][3])));
            smaxl[g] = mx;
            dmax = fmaxf(dmax, mx - m_run[g]);
        }
        if (!__all(dmax <= 8.0f)) {        // rare after warm-up
#pragma unroll
            for (int g = 0; g < 2; ++g) {
                float mx = smaxl[g];
                mx = fmaxf(mx, __shfl_xor(mx, 16, 64));
                mx = fmaxf(mx, __shfl_xor(mx, 32, 64));
                float mnew = fmaxf(m_run[g], mx);
                float c = exp2f(m_run[g] - mnew);
                m_run[g] = mnew;
                l_part[g] *= c;
#pragma unroll
                for (int ds = 0; ds < 8; ++ds) acc[g][ds] *= c;
            }
        }

#pragma unroll
        for (int g = 0; g < 2; ++g) {
            bf16x4v pbv[2];
#pragma unroll
            for (int ms = 0; ms < 2; ++ms)
#pragma unroll
                for (int r = 0; r < 4; ++r) {
                    float p = exp2f(s[g][ms][r] - m_run[g]);   // p <= 2^8
                    __bf16 pb = (__bf16)p;
                    l_part[g] += (float)pb;
                    pbv[ms][r] = pb;
                }
            const int base = (w * 2 + g) * 1024 + l15 * 64;
#pragma unroll
            for (int ms = 0; ms < 2; ++ms)
                *reinterpret_cast<bf16x4v*>(reinterpret_cast<char*>(p_lds)
                    + base + ms * 32 + lhi * 8) = pbv[ms];
            bf16x8 pa = lds_read16(p_lds, base + lhi * 16);
            __builtin_amdgcn_s_setprio(1);
#pragma unroll
            for (int ds = 0; ds < 8; ++ds)
                acc[g][ds] = __builtin_amdgcn_mfma_f32_16x16x32_bf16(
                    vf[ds], pa, acc[g][ds], 0, 0, 0);
            __builtin_amdgcn_s_setprio(0);
        }
    };

    // ---- counted-vmcnt double-barrier pipeline (per body: 4 stage + 2 mask) ----
    auto body = [&](unsigned short* cur, unsigned short* nxt,
                    unsigned int (&mkc)[2], unsigned int (&mkn)[2], int t) {
        int tn = (t + 1 < ntl) ? t + 1 : ntl - 1;
        stage(nxt, ptbase + tn);
        mkn[0] = pmr0[ptbase + tn];
        mkn[1] = pmr1[ptbase + tn];
        // drain previous body's 6 VMEM ops; this body's 6 stay in flight
        asm volatile("s_waitcnt vmcnt(6)" ::: "memory");
        __builtin_amdgcn_sched_barrier(0);
        __builtin_amdgcn_s_barrier();
        __builtin_amdgcn_sched_barrier(0);
        compute(cur, mkc[0], mkc[1]);
        __builtin_amdgcn_sched_barrier(0);
        __builtin_amdgcn_s_barrier();     // WAR: all waves done reading cur
        __builtin_amdgcn_sched_barrier(0);
    };

    unsigned int muA[2], muB[2];
    stage(stA, ptbase);
    muA[0] = pmr0[ptbase];
    muA[1] = pmr1[ptbase];
    for (int t = 0; t < ntl; t += 2) {
        body(stA, stB, muA, muB, t);
        body(stB, stA, muB, muA, t + 1);
    }

    // ---- epilogue
#pragma unroll
    for (int g = 0; g < 2; ++g) {
        float rs = l_part[g];
        rs += __shfl_xor(rs, 16, 64);
        rs += __shfl_xor(rs, 32, 64);
        l_part[g] = rs;
    }

    float* op = (sp == 0) ? out : (opart1 + (size_t)(sp - 1) * NR * ND);
#pragma unroll
    for (int g = 0; g < 2; ++g) {
        const size_t rowbase = (bN + q0w + g * 16 + l15) * ND;
#pragma unroll
        for (int ds = 0; ds < 8; ++ds)
            *reinterpret_cast<f32x4*>(op + rowbase + 16 * ds + 4 * lhi) = acc[g][ds];
    }
    if (lhi == 0) {
#pragma unroll
        for (int g = 0; g < 2; ++g) {
            size_t gr = bN + q0w + g * 16 + l15;
            *reinterpret_cast<float2*>(ml + ((size_t)sp * NR + gr) * 2) =
                make_float2(m_run[g], l_part[g]);
        }
    }
}

// ---------------- Kernel 3: merge the KV-splits (m is log2-domain) -------------
__global__ __launch_bounds__(256) void merge_splits(
    float* __restrict__ out, const float* __restrict__ opart1,
    const float* __restrict__ ml, int nsplit)
{
    int idx = blockIdx.x * 256 + threadIdx.x;
    int row = idx >> 5;
    int d4 = (idx & 31) * 4;
    float mmax = ml[(size_t)row * 2];
    for (int sp = 1; sp < nsplit; ++sp)
        mmax = fmaxf(mmax, ml[((size_t)sp * NR + row) * 2]);
    f32x4 o0 = *reinterpret_cast<const f32x4*>(out + (size_t)row * ND + d4);
    float w0 = exp2f(ml[(size_t)row * 2] - mmax);
    float lsum = ml[(size_t)row * 2 + 1] * w0;
    f32x4 acc;
#pragma unroll
    for (int j = 0; j < 4; ++j) acc[j] = o0[j] * w0;
    for (int sp = 1; sp < nsplit; ++sp) {
        float m_s = ml[((size_t)sp * NR + row) * 2];
        float l_s = ml[((size_t)sp * NR + row) * 2 + 1];
        float ws_ = exp2f(m_s - mmax);
        f32x4 os = *reinterpret_cast<const f32x4*>(opart1 + ((size_t)(sp - 1) * NR + row) * ND + d4);
#pragma unroll
        for (int j = 0; j < 4; ++j) acc[j] += os[j] * ws_;
        lsum += l_s * ws_;
    }
    float inv = 1.0f / lsum;
    f32x4 r;
#pragma unroll
    for (int j = 0; j < 4; ++j) r[j] = acc[j] * inv;
    *reinterpret_cast<f32x4*>(out + (size_t)row * ND + d4) = r;
}

extern "C" void kernel_launch(void* const* d_in, const int* in_sizes, int n_in,
                              void* d_out, int out_size, void* d_ws, size_t ws_size,
                              hipStream_t stream) {
    const float* h  = (const float*)d_in[0];
    const int* adj  = (const int*)d_in[1];
    const float* Wq = (const float*)d_in[2];
    const float* bq = (const float*)d_in[3];
    const float* Wk = (const float*)d_in[4];
    const float* bk = (const float*)d_in[5];
    const float* Wv = (const float*)d_in[6];
    const float* bv = (const float*)d_in[7];
    float* out = (float*)d_out;

    unsigned short* qws  = (unsigned short*)d_ws;
    unsigned short* kws  = qws + QKVE;
    unsigned short* vsws = kws + QKVE;
    float* opart1 = (float*)(vsws + QKVE);

    const size_t pm_bytes = (size_t)NB * NN * (NN / 8);          // 8.39 MB
    const size_t need4 = 3 * QKVE * 2 + 3 * QKVE * 4 + 4 * (size_t)NR * 2 * 4 + pm_bytes;
    const int nsplit = (ws_size >= need4) ? 4 : 2;
    float* mlws = opart1 + (size_t)(nsplit - 1) * NR * ND;
    unsigned int* pmws = (unsigned int*)(mlws + (size_t)nsplit * NR * 2);
    const int ntl = (NN / KVB) / nsplit;                          // 32 or 64

    // 1/(sqrt(128) * ln2): scores land in log2 units -> exp2 softmax
    const float qscale = (float)(0.08838834764831845 / 0.6931471805599453);

    pack_proj<<<dim3(1024 + 768), 256, 0, stream>>>(
        adj, (unsigned long long*)pmws,
        h, Wq, bq, Wk, bk, Wv, bv, qws, kws, vsws, qscale);
    attn<<<dim3(32 * 4 * nsplit), 256, 0, stream>>>(
        qws, kws, vsws, pmws, out, opart1, mlws, ntl);
    merge_splits<<<dim3(NR * 32 / 256), 256, 0, stream>>>(out, opart1, mlws, nsplit);
}

// Round 16
// 155.850 us; speedup vs baseline: 1.3924x; 1.0250x over previous
//
#include <hip/hip_runtime.h>
#include <stdint.h>
#include <math.h>

#define NB 4
#define NN 4096
#define NF 256
#define ND 128
#define KVB 32
#define NR (NB * NN)
#define QKVE ((size_t)NR * ND)      // 2,097,152 elements

typedef __bf16 bf16x8 __attribute__((ext_vector_type(8)));
typedef __bf16 bf16x4v __attribute__((ext_vector_type(4)));
typedef float f32x4 __attribute__((ext_vector_type(4)));
typedef unsigned short u16x4 __attribute__((ext_vector_type(4)));

__device__ __forceinline__ unsigned short f2bf(float f) {
    union { float f; uint32_t u; } v; v.f = f;
    uint32_t r = (v.u + 0x7FFFu + ((v.u >> 16) & 1u)) >> 16;
    return (unsigned short)r;
}
__device__ __forceinline__ bf16x8 lds_read16(const unsigned short* base, int byte_off) {
    return *reinterpret_cast<const bf16x8*>(reinterpret_cast<const char*>(base) + byte_off);
}
__device__ __forceinline__ void gld_lds16(const void* g, void* l) {
    __builtin_amdgcn_global_load_lds(
        (const __attribute__((address_space(1))) void*)g,
        (__attribute__((address_space(3))) void*)l, 16, 0, 0);
}

// ------- Kernel 0+1 fused: pack adj bitmask (blocks 0..1023) + QKV proj -------
// (identical to round 13 — proven)
__global__ __launch_bounds__(256) void pack_proj(
    const int* __restrict__ adj, unsigned long long* __restrict__ pm64,
    const float* __restrict__ h,
    const float* __restrict__ Wq, const float* __restrict__ bq,
    const float* __restrict__ Wk, const float* __restrict__ bk,
    const float* __restrict__ Wv, const float* __restrict__ bv,
    unsigned short* __restrict__ qo, unsigned short* __restrict__ ko,
    unsigned short* __restrict__ vs, float qscale)
{
    __shared__ unsigned short h_lds[64 * 128];
    __shared__ unsigned short w_lds[128 * 128];

    const int tid = threadIdx.x;
    const int lane = tid & 63;

    if (blockIdx.x < 1024) {
        const int w = tid >> 6;
        const size_t base = ((size_t)blockIdx.x * 4 + w) * 256;
        for (int o = 0; o < 32; ++o) {
            const size_t wb = base + o * 8;
            int v[8];
#pragma unroll
            for (int u = 0; u < 8; ++u)
                v[u] = adj[(wb + u) * 64 + lane];
            unsigned long long m[8];
#pragma unroll
            for (int u = 0; u < 8; ++u)
                m[u] = __ballot(v[u] != 0);
            if (lane == 0) {
#pragma unroll
                for (int u = 0; u < 8; u += 2) {
                    ulonglong2 st; st.x = m[u]; st.y = m[u + 1];
                    *reinterpret_cast<ulonglong2*>(pm64 + wb + u) = st;
                }
            }
        }
        return;
    }

    const int idx = blockIdx.x - 1024;
    const int proj = idx >> 8;          // 0=Q,1=K,2=V
    const int R0 = (idx & 255) * 64;
    const int wv = tid >> 6;
    const int l15 = lane & 15;
    const int lhi = lane >> 4;

    const float* W    = proj == 0 ? Wq : (proj == 1 ? Wk : Wv);
    const float* bias = proj == 0 ? bq : (proj == 1 ? bk : bv);
    const float scale = proj == 0 ? qscale : 1.0f;

    f32x4 acc[8];
#pragma unroll
    for (int i = 0; i < 8; ++i) acc[i] = f32x4{0.f, 0.f, 0.f, 0.f};

    for (int kc = 0; kc < 2; ++kc) {
        const int c0 = kc * 128;
        __syncthreads();
#pragma unroll
        for (int p = 0; p < 8; ++p) {
            int i2 = p * 256 + tid;
            int row = i2 >> 5;
            int seg = i2 & 31;
            f32x4 hv = *reinterpret_cast<const f32x4*>(h + (size_t)(R0 + row) * NF + c0 + seg * 4);
            u16x4 hb;
            hb[0] = f2bf(hv[0]); hb[1] = f2bf(hv[1]); hb[2] = f2bf(hv[2]); hb[3] = f2bf(hv[3]);
            int byte = (row * 256 + seg * 8) ^ ((row & 7) << 4);
            *reinterpret_cast<u16x4*>(reinterpret_cast<char*>(h_lds) + byte) = hb;
        }
#pragma unroll
        for (int p = 0; p < 16; ++p) {
            int i2 = p * 256 + tid;
            int row = i2 >> 5;
            int seg = i2 & 31;
            f32x4 wv4 = *reinterpret_cast<const f32x4*>(W + (size_t)row * NF + c0 + seg * 4);
            u16x4 wb;
            wb[0] = f2bf(wv4[0]); wb[1] = f2bf(wv4[1]); wb[2] = f2bf(wv4[2]); wb[3] = f2bf(wv4[3]);
            int byte = (row * 256 + seg * 8) ^ ((row & 7) << 4);
            *reinterpret_cast<u16x4*>(reinterpret_cast<char*>(w_lds) + byte) = wb;
        }
        __syncthreads();
        const int arow = 16 * wv + l15;
#pragma unroll
        for (int ks = 0; ks < 4; ++ks) {
            int k = ks * 32 + 8 * lhi;
            bf16x8 a = lds_read16(h_lds, (arow * 256 + k * 2) ^ ((arow & 7) << 4));
#pragma unroll
            for (int cs = 0; cs < 8; ++cs) {
                int d = 16 * cs + l15;
                bf16x8 b = lds_read16(w_lds, (d * 256 + k * 2) ^ ((d & 7) << 4));
                acc[cs] = __builtin_amdgcn_mfma_f32_16x16x32_bf16(a, b, acc[cs], 0, 0, 0);
            }
        }
    }
    if (proj < 2) {
        unsigned short* out = proj == 0 ? qo : ko;
#pragma unroll
        for (int cs = 0; cs < 8; ++cs) {
            int d = 16 * cs + l15;
            float bb = bias[d];
#pragma unroll
            for (int j = 0; j < 4; ++j) {
                int row = R0 + 16 * wv + 4 * lhi + j;
                out[(size_t)row * ND + d] = f2bf((acc[cs][j] + bb) * scale);
            }
        }
    } else {
        const int bb_ = R0 >> 12;
        const int nb_ = (R0 & (NN - 1)) + 16 * wv + 4 * lhi;
        const int pt = nb_ >> 5;
        const int ch = (nb_ >> 3) & 3;
        const int mm0 = nb_ & 7;
#pragma unroll
        for (int cs = 0; cs < 8; ++cs) {
            int d = 16 * cs + l15;
            float bb = bias[d];
            u16x4 o;
#pragma unroll
            for (int j = 0; j < 4; ++j) o[j] = f2bf(acc[cs][j] + bb);
            size_t oidx = ((size_t)(bb_ * 128 + pt)) * 4096 + ch * 1024 + d * 8 + mm0;
            *reinterpret_cast<u16x4*>(vs + oidx) = o;
        }
    }
}

// -------- Kernel 2: LDS-staged flash attention, 16 q-rows/wave, 4 waves/SIMD ---
// r16 change vs r13: halve per-wave q rows (32->16) so acc = 32 AGPR (not 64)
// and total regs fit the 128 cap -> 4 waves/SIMD (occupancy cliff is binary:
// <=128 regs = 4/SIMD, >128 = 2/SIMD; all prior (256,4) spills had acc=64).
// Grid 1024 = 4 blocks/CU x 4 waves = 16 waves/CU. Same staged-LDS structure,
// plain __syncthreads (r15's counted vmcnt regressed). Numerics unchanged.
__global__ __launch_bounds__(256, 4) void attn(
    const unsigned short* __restrict__ Q,   // [B*N,128] bf16, scaled 1/(sqrt(128)*ln2)
    const unsigned short* __restrict__ K,   // [B*N,128] bf16 row-major
    const unsigned short* __restrict__ VS,  // tiled V (see proj)
    const unsigned int* __restrict__ pm,    // [B*N][128] packed adj words
    float* __restrict__ out,                // split-0 partial O (and final out)
    float* __restrict__ opart1,             // splits 1.. partial O (f32)
    float* __restrict__ ml,                 // [nsplit][NR][2] (m, l) log2-domain
    int ntl)                                // tiles per split (32 or 64)
{
    __shared__ unsigned short stA[8192];   // [0..4095]=K frags, [4096..8191]=V frags
    __shared__ unsigned short stB[8192];
    __shared__ unsigned short p_lds[2048]; // 4 waves x 1KB P^T tiles

    const int tid = threadIdx.x;
    const int lane = tid & 63;
    const int w = tid >> 6;
    const int l15 = lane & 15;
    const int lhi = lane >> 4;

    const int flat = blockIdx.x;
    const int x = flat & 7;
    const int rest = flat >> 3;
    const int qt = rest & 63;
    const int s2 = rest >> 6;
    const int combo = x + 8 * s2;          // b = combo&3 constant per XCD slot
    const int b = combo & 3;
    const int sp = combo >> 2;
    const int q0w = qt * 64 + w * 16;      // wave's first q row (in batch)
    const size_t bN = (size_t)b * NN;
    const int ptbase = sp * ntl;

    const unsigned short* Kb = K + bN * ND;
    const unsigned short* Vbase = VS + (size_t)b * 128 * 4096;

    bf16x8 qf[4];
#pragma unroll
    for (int ks = 0; ks < 4; ++ks)
        qf[ks] = *reinterpret_cast<const bf16x8*>(
            Q + (bN + q0w + l15) * ND + ks * 32 + 8 * lhi);

    const unsigned int* pmr = pm + (bN + (size_t)(q0w + l15)) * 128;

    f32x4 acc[8];
#pragma unroll
    for (int i = 0; i < 8; ++i) acc[i] = f32x4{0.f, 0.f, 0.f, 0.f};
    float m_run = -INFINITY;
    float l_part = 0.f;

    auto stage = [&](unsigned short* st, int pt) {
        const int m0 = pt * KVB;
#pragma unroll
        for (int i = 0; i < 4; ++i) {
            int c = w * 4 + i;                  // 0..15, wave-uniform
            if (c < 8) {                        // K frag block c = ms*4+ks
                int ms = c >> 2, ks = c & 3;
                const unsigned short* src = Kb
                    + (size_t)(m0 + ms * 16 + l15) * ND + ks * 32 + lhi * 8;
                gld_lds16(src, st + c * 512);
            } else {                            // V chunk (VS tile is the LDS image)
                int vi = c - 8;
                const unsigned short* src = Vbase + (size_t)pt * 4096 + vi * 512 + lane * 8;
                gld_lds16(src, st + 4096 + vi * 512);
            }
        }
    };

    auto compute = [&](const unsigned short* st, unsigned int mw) {
        // ---- S^T = mfma(K, Q), per-ms to keep transients small
        f32x4 s0 = f32x4{0.f, 0.f, 0.f, 0.f}, s1 = f32x4{0.f, 0.f, 0.f, 0.f};
        __builtin_amdgcn_s_setprio(1);
        {
#pragma unroll
            for (int ks = 0; ks < 4; ++ks) {
                bf16x8 kf = lds_read16(st, ks * 1024 + lane * 16);
                s0 = __builtin_amdgcn_mfma_f32_16x16x32_bf16(kf, qf[ks], s0, 0, 0, 0);
            }
#pragma unroll
            for (int ks = 0; ks < 4; ++ks) {
                bf16x8 kf = lds_read16(st, (4 + ks) * 1024 + lane * 16);
                s1 = __builtin_amdgcn_mfma_f32_16x16x32_bf16(kf, qf[ks], s1, 0, 0, 0);
            }
        }
        __builtin_amdgcn_s_setprio(0);

        // ---- mask + local max + defer-max vote
        unsigned int mwg = mw >> (4 * lhi);
#pragma unroll
        for (int r = 0; r < 4; ++r) {
            if (!((mwg >> r) & 1u))        s0[r] = -1.0e30f;
            if (!((mwg >> (16 + r)) & 1u)) s1[r] = -1.0e30f;
        }
        float mx = fmaxf(fmaxf(fmaxf(s0[0], s0[1]), fmaxf(s0[2], s0[3])),
                         fmaxf(fmaxf(s1[0], s1[1]), fmaxf(s1[2], s1[3])));
        if (!__all(mx - m_run <= 8.0f)) {      // rare after warm-up
            mx = fmaxf(mx, __shfl_xor(mx, 16, 64));
            mx = fmaxf(mx, __shfl_xor(mx, 32, 64));
            float mnew = fmaxf(m_run, mx);
            float c = exp2f(m_run - mnew);
            m_run = mnew;
            l_part *= c;
#pragma unroll
            for (int ds = 0; ds < 8; ++ds) acc[ds] *= c;
        }

        // ---- p (bf16-rounded; l matches PV weights exactly)
        bf16x4v pbv0, pbv1;
#pragma unroll
        for (int r = 0; r < 4; ++r) {
            float p0 = exp2f(s0[r] - m_run);
            float p1 = exp2f(s1[r] - m_run);
            __bf16 b0 = (__bf16)p0, b1 = (__bf16)p1;
            l_part += (float)b0 + (float)b1;
            pbv0[r] = b0; pbv1[r] = b1;
        }
        const int base = w * 1024 + l15 * 64;
        *reinterpret_cast<bf16x4v*>(reinterpret_cast<char*>(p_lds) + base + lhi * 8) = pbv0;
        *reinterpret_cast<bf16x4v*>(reinterpret_cast<char*>(p_lds) + base + 32 + lhi * 8) = pbv1;
        bf16x8 pa = lds_read16(p_lds, base + lhi * 16);  // P[q=l15][m=8lhi..]

        // ---- O^T += mfma(V, P), per-ds (small transients)
        __builtin_amdgcn_s_setprio(1);
#pragma unroll
        for (int ds = 0; ds < 8; ++ds) {
            bf16x8 vf = lds_read16(st + 4096, lhi * 2048 + ds * 256 + l15 * 16);
            acc[ds] = __builtin_amdgcn_mfma_f32_16x16x32_bf16(vf, pa, acc[ds], 0, 0, 0);
        }
        __builtin_amdgcn_s_setprio(0);
    };

    // ---- pipeline: stage(t+1) issued before compute(t); sync per tile
    stage(stA, ptbase);
    __syncthreads();

    uint2 mk = *reinterpret_cast<const uint2*>(pmr + ptbase);
    for (int t = 0; t < ntl; t += 2) {
        int tn = (t + 2 < ntl) ? t + 2 : t;
        uint2 nk = *reinterpret_cast<const uint2*>(pmr + ptbase + tn);

        stage(stB, ptbase + t + 1);
        compute(stA, mk.x);
        __syncthreads();
        stage(stA, ptbase + (t + 2 < ntl ? t + 2 : ntl - 1));
        compute(stB, mk.y);
        __syncthreads();

        mk = nk;
    }

    // ---- epilogue: deferred cross-lhi l reduction (2 shfls, linear=exact)
    {
        float rs = l_part;
        rs += __shfl_xor(rs, 16, 64);
        rs += __shfl_xor(rs, 32, 64);
        l_part = rs;
    }

    float* op = (sp == 0) ? out : (opart1 + (size_t)(sp - 1) * NR * ND);
    const size_t rowbase = (bN + q0w + l15) * ND;
#pragma unroll
    for (int ds = 0; ds < 8; ++ds)
        *reinterpret_cast<f32x4*>(op + rowbase + 16 * ds + 4 * lhi) = acc[ds];
    if (lhi == 0) {
        size_t gr = bN + q0w + l15;
        *reinterpret_cast<float2*>(ml + ((size_t)sp * NR + gr) * 2) =
            make_float2(m_run, l_part);
    }
}

// ---------------- Kernel 3: merge the KV-splits (m is log2-domain) -------------
__global__ __launch_bounds__(256) void merge_splits(
    float* __restrict__ out, const float* __restrict__ opart1,
    const float* __restrict__ ml, int nsplit)
{
    int idx = blockIdx.x * 256 + threadIdx.x;
    int row = idx >> 5;
    int d4 = (idx & 31) * 4;
    float mmax = ml[(size_t)row * 2];
    for (int sp = 1; sp < nsplit; ++sp)
        mmax = fmaxf(mmax, ml[((size_t)sp * NR + row) * 2]);
    f32x4 o0 = *reinterpret_cast<const f32x4*>(out + (size_t)row * ND + d4);
    float w0 = exp2f(ml[(size_t)row * 2] - mmax);
    float lsum = ml[(size_t)row * 2 + 1] * w0;
    f32x4 acc;
#pragma unroll
    for (int j = 0; j < 4; ++j) acc[j] = o0[j] * w0;
    for (int sp = 1; sp < nsplit; ++sp) {
        float m_s = ml[((size_t)sp * NR + row) * 2];
        float l_s = ml[((size_t)sp * NR + row) * 2 + 1];
        float ws_ = exp2f(m_s - mmax);
        f32x4 os = *reinterpret_cast<const f32x4*>(opart1 + ((size_t)(sp - 1) * NR + row) * ND + d4);
#pragma unroll
        for (int j = 0; j < 4; ++j) acc[j] += os[j] * ws_;
        lsum += l_s * ws_;
    }
    float inv = 1.0f / lsum;
    f32x4 r;
#pragma unroll
    for (int j = 0; j < 4; ++j) r[j] = acc[j] * inv;
    *reinterpret_cast<f32x4*>(out + (size_t)row * ND + d4) = r;
}

extern "C" void kernel_launch(void* const* d_in, const int* in_sizes, int n_in,
                              void* d_out, int out_size, void* d_ws, size_t ws_size,
                              hipStream_t stream) {
    const float* h  = (const float*)d_in[0];
    const int* adj  = (const int*)d_in[1];
    const float* Wq = (const float*)d_in[2];
    const float* bq = (const float*)d_in[3];
    const float* Wk = (const float*)d_in[4];
    const float* bk = (const float*)d_in[5];
    const float* Wv = (const float*)d_in[6];
    const float* bv = (const float*)d_in[7];
    float* out = (float*)d_out;

    unsigned short* qws  = (unsigned short*)d_ws;
    unsigned short* kws  = qws + QKVE;
    unsigned short* vsws = kws + QKVE;
    float* opart1 = (float*)(vsws + QKVE);

    const size_t pm_bytes = (size_t)NB * NN * (NN / 8);          // 8.39 MB
    const size_t need4 = 3 * QKVE * 2 + 3 * QKVE * 4 + 4 * (size_t)NR * 2 * 4 + pm_bytes;
    const int nsplit = (ws_size >= need4) ? 4 : 2;
    float* mlws = opart1 + (size_t)(nsplit - 1) * NR * ND;
    unsigned int* pmws = (unsigned int*)(mlws + (size_t)nsplit * NR * 2);
    const int ntl = (NN / KVB) / nsplit;                          // 32 or 64

    // 1/(sqrt(128) * ln2): scores land in log2 units -> exp2 softmax
    const float qscale = (float)(0.08838834764831845 / 0.6931471805599453);

    pack_proj<<<dim3(1024 + 768), 256, 0, stream>>>(
        adj, (unsigned long long*)pmws,
        h, Wq, bq, Wk, bk, Wv, bv, qws, kws, vsws, qscale);
    attn<<<dim3(64 * 4 * nsplit), 256, 0, stream>>>(
        qws, kws, vsws, pmws, out, opart1, mlws, ntl);
    merge_splits<<<dim3(NR * 32 / 256), 256, 0, stream>>>(out, opart1, mlws, nsplit);
}

// Round 17
// 124.628 us; speedup vs baseline: 1.7412x; 1.2505x over previous
//
#include <hip/hip_runtime.h>
#include <stdint.h>
#include <math.h>

#define NB 4
#define NN 4096
#define NF 256
#define ND 128
#define KVB 32
#define NR (NB * NN)
#define QKVE ((size_t)NR * ND)      // 2,097,152 elements

typedef __bf16 bf16x8 __attribute__((ext_vector_type(8)));
typedef __bf16 bf16x4v __attribute__((ext_vector_type(4)));
typedef float f32x4 __attribute__((ext_vector_type(4)));
typedef int i32x4 __attribute__((ext_vector_type(4)));
typedef unsigned short u16x4 __attribute__((ext_vector_type(4)));

__device__ __forceinline__ unsigned short f2bf(float f) {
    union { float f; uint32_t u; } v; v.f = f;
    uint32_t r = (v.u + 0x7FFFu + ((v.u >> 16) & 1u)) >> 16;
    return (unsigned short)r;
}
__device__ __forceinline__ bf16x8 lds_read16(const unsigned short* base, int byte_off) {
    return *reinterpret_cast<const bf16x8*>(reinterpret_cast<const char*>(base) + byte_off);
}
__device__ __forceinline__ void gld_lds16(const void* g, void* l) {
    __builtin_amdgcn_global_load_lds(
        (const __attribute__((address_space(1))) void*)g,
        (__attribute__((address_space(3))) void*)l, 16, 0, 0);
}

// ---------------- Kernel 1: QKV projection (proven core, now standalone) -------
// V written in B-frag tile order: VS[b][tile(128)][chunk(4)][d(128)][m8]
__global__ __launch_bounds__(256) void qkv_proj(
    const float* __restrict__ h,
    const float* __restrict__ Wq, const float* __restrict__ bq,
    const float* __restrict__ Wk, const float* __restrict__ bk,
    const float* __restrict__ Wv, const float* __restrict__ bv,
    unsigned short* __restrict__ qo, unsigned short* __restrict__ ko,
    unsigned short* __restrict__ vs, float qscale)
{
    __shared__ unsigned short h_lds[64 * 128];
    __shared__ unsigned short w_lds[128 * 128];

    const int tid = threadIdx.x;
    const int lane = tid & 63;
    const int proj = blockIdx.x >> 8;          // 0=Q,1=K,2=V
    const int R0 = (blockIdx.x & 255) * 64;
    const int wv = tid >> 6;
    const int l15 = lane & 15;
    const int lhi = lane >> 4;

    const float* W    = proj == 0 ? Wq : (proj == 1 ? Wk : Wv);
    const float* bias = proj == 0 ? bq : (proj == 1 ? bk : bv);
    const float scale = proj == 0 ? qscale : 1.0f;

    f32x4 acc[8];
#pragma unroll
    for (int i = 0; i < 8; ++i) acc[i] = f32x4{0.f, 0.f, 0.f, 0.f};

    for (int kc = 0; kc < 2; ++kc) {
        const int c0 = kc * 128;
        __syncthreads();
#pragma unroll
        for (int p = 0; p < 8; ++p) {
            int i2 = p * 256 + tid;
            int row = i2 >> 5;
            int seg = i2 & 31;
            f32x4 hv = *reinterpret_cast<const f32x4*>(h + (size_t)(R0 + row) * NF + c0 + seg * 4);
            u16x4 hb;
            hb[0] = f2bf(hv[0]); hb[1] = f2bf(hv[1]); hb[2] = f2bf(hv[2]); hb[3] = f2bf(hv[3]);
            int byte = (row * 256 + seg * 8) ^ ((row & 7) << 4);
            *reinterpret_cast<u16x4*>(reinterpret_cast<char*>(h_lds) + byte) = hb;
        }
#pragma unroll
        for (int p = 0; p < 16; ++p) {
            int i2 = p * 256 + tid;
            int row = i2 >> 5;
            int seg = i2 & 31;
            f32x4 wv4 = *reinterpret_cast<const f32x4*>(W + (size_t)row * NF + c0 + seg * 4);
            u16x4 wb;
            wb[0] = f2bf(wv4[0]); wb[1] = f2bf(wv4[1]); wb[2] = f2bf(wv4[2]); wb[3] = f2bf(wv4[3]);
            int byte = (row * 256 + seg * 8) ^ ((row & 7) << 4);
            *reinterpret_cast<u16x4*>(reinterpret_cast<char*>(w_lds) + byte) = wb;
        }
        __syncthreads();
        const int arow = 16 * wv + l15;
#pragma unroll
        for (int ks = 0; ks < 4; ++ks) {
            int k = ks * 32 + 8 * lhi;
            bf16x8 a = lds_read16(h_lds, (arow * 256 + k * 2) ^ ((arow & 7) << 4));
#pragma unroll
            for (int cs = 0; cs < 8; ++cs) {
                int d = 16 * cs + l15;
                bf16x8 b = lds_read16(w_lds, (d * 256 + k * 2) ^ ((d & 7) << 4));
                acc[cs] = __builtin_amdgcn_mfma_f32_16x16x32_bf16(a, b, acc[cs], 0, 0, 0);
            }
        }
    }
    if (proj < 2) {
        unsigned short* out = proj == 0 ? qo : ko;
#pragma unroll
        for (int cs = 0; cs < 8; ++cs) {
            int d = 16 * cs + l15;
            float bb = bias[d];
#pragma unroll
            for (int j = 0; j < 4; ++j) {
                int row = R0 + 16 * wv + 4 * lhi + j;
                out[(size_t)row * ND + d] = f2bf((acc[cs][j] + bb) * scale);
            }
        }
    } else {
        const int bb_ = R0 >> 12;
        const int nb_ = (R0 & (NN - 1)) + 16 * wv + 4 * lhi;
        const int pt = nb_ >> 5;
        const int ch = (nb_ >> 3) & 3;
        const int mm0 = nb_ & 7;
#pragma unroll
        for (int cs = 0; cs < 8; ++cs) {
            int d = 16 * cs + l15;
            float bb = bias[d];
            u16x4 o;
#pragma unroll
            for (int j = 0; j < 4; ++j) o[j] = f2bf(acc[cs][j] + bb);
            size_t oidx = ((size_t)(bb_ * 128 + pt)) * 4096 + ch * 1024 + d * 8 + mm0;
            *reinterpret_cast<u16x4*>(vs + oidx) = o;
        }
    }
}

// -------- Kernel 2: LDS-staged flash attention, DIRECT adj masking -------------
// r17 change vs r13: pack_adj pass DELETED. With KV-split each adj[b][q][m] is
// consumed by exactly ONE block, so attn reads adj directly: per lane 8 ints
// per tile (2x int4 per g), 1KB distinct/instr in 64B segments, prefetched one
// tile ahead (compute-phase latency cover). The 268MB adj stream overlaps
// attn's compute instead of costing a serialized ~45us pack pass.
// Everything else identical to r13 (best passing config, 152.8us).
__global__ __launch_bounds__(256, 2) void attn(
    const unsigned short* __restrict__ Q,   // [B*N,128] bf16, scaled 1/(sqrt(128)*ln2)
    const unsigned short* __restrict__ K,   // [B*N,128] bf16 row-major
    const unsigned short* __restrict__ VS,  // tiled V (see proj)
    const int* __restrict__ adj,            // [B,N,N] i32
    float* __restrict__ out,                // split-0 partial O (and final out)
    float* __restrict__ opart1,             // splits 1.. partial O (f32)
    float* __restrict__ ml,                 // [nsplit][NR][2] (m, l) log2-domain
    int ntl)                                // tiles per split (32 or 64)
{
    __shared__ unsigned short stA[8192];   // [0..4095]=K frags, [4096..8191]=V frags
    __shared__ unsigned short stB[8192];
    __shared__ unsigned short p_lds[4096]; // 4 waves x 2 groups x 1KB P^T tiles

    const int tid = threadIdx.x;
    const int lane = tid & 63;
    const int w = tid >> 6;
    const int l15 = lane & 15;
    const int lhi = lane >> 4;

    const int flat = blockIdx.x;
    const int x = flat & 7;
    const int rest = flat >> 3;
    const int qt = rest & 31;
    const int s2 = rest >> 5;
    const int combo = x + 8 * s2;
    const int b = combo & 3;
    const int sp = combo >> 2;
    const int q0w = qt * 128 + w * 32;
    const size_t bN = (size_t)b * NN;
    const int ptbase = sp * ntl;

    const unsigned short* Kb = K + bN * ND;
    const unsigned short* Vbase = VS + (size_t)b * 128 * 4096;
    // per-lane adj base: row (q0w + g*16 + l15), col segment 4*lhi
    const int* adjb = adj + (size_t)b * NN * NN + (size_t)(q0w + l15) * NN + 4 * lhi;

    bf16x8 qf[2][4];
#pragma unroll
    for (int g = 0; g < 2; ++g)
#pragma unroll
        for (int ks = 0; ks < 4; ++ks)
            qf[g][ks] = *reinterpret_cast<const bf16x8*>(
                Q + (bN + q0w + g * 16 + l15) * ND + ks * 32 + 8 * lhi);

    f32x4 acc[2][8];
#pragma unroll
    for (int g = 0; g < 2; ++g)
#pragma unroll
        for (int i = 0; i < 8; ++i) acc[g][i] = f32x4{0.f, 0.f, 0.f, 0.f};
    float m_run[2] = {-INFINITY, -INFINITY};
    float l_part[2] = {0.f, 0.f};

    auto stage = [&](unsigned short* st, int pt) {
        const int m0 = pt * KVB;
#pragma unroll
        for (int i = 0; i < 4; ++i) {
            int c = w * 4 + i;                  // 0..15, wave-uniform
            if (c < 8) {                        // K frag block c = ms*4+ks
                int ms = c >> 2, ks = c & 3;
                const unsigned short* src = Kb
                    + (size_t)(m0 + ms * 16 + l15) * ND + ks * 32 + lhi * 8;
                gld_lds16(src, st + c * 512);
            } else {                            // V chunk (VS tile is the LDS image)
                int vi = c - 8;
                const unsigned short* src = Vbase + (size_t)pt * 4096 + vi * 512 + lane * 8;
                gld_lds16(src, st + 4096 + vi * 512);
            }
        }
    };
    // direct adj mask load: this lane's 8 ints per g (rows q0w+16g+l15)
    auto adjld = [&](i32x4 (&ma)[2][2], int pt) {
        const int m0 = pt * KVB;
#pragma unroll
        for (int g = 0; g < 2; ++g)
#pragma unroll
            for (int ms = 0; ms < 2; ++ms)
                ma[g][ms] = *reinterpret_cast<const i32x4*>(
                    adjb + (size_t)(g * 16) * NN + m0 + 16 * ms);
    };

    auto compute = [&](const unsigned short* st, const i32x4 (&ma)[2][2]) {
        bf16x8 kf[2][4];
#pragma unroll
        for (int ms = 0; ms < 2; ++ms)
#pragma unroll
            for (int ks = 0; ks < 4; ++ks)
                kf[ms][ks] = lds_read16(st, (ms * 4 + ks) * 1024 + lane * 16);

        f32x4 s[2][2];
#pragma unroll
        for (int g = 0; g < 2; ++g)
#pragma unroll
            for (int ms = 0; ms < 2; ++ms) s[g][ms] = f32x4{0.f, 0.f, 0.f, 0.f};
        __builtin_amdgcn_s_setprio(1);
#pragma unroll
        for (int g = 0; g < 2; ++g)
#pragma unroll
            for (int ms = 0; ms < 2; ++ms)
#pragma unroll
                for (int ks = 0; ks < 4; ++ks)
                    s[g][ms] = __builtin_amdgcn_mfma_f32_16x16x32_bf16(
                        kf[ms][ks], qf[g][ks], s[g][ms], 0, 0, 0);
        __builtin_amdgcn_s_setprio(0);

        bf16x8 vf[8];
#pragma unroll
        for (int ds = 0; ds < 8; ++ds)
            vf[ds] = lds_read16(st + 4096, lhi * 2048 + ds * 256 + l15 * 16);

        float smaxl[2];
        float dmax = -INFINITY;
#pragma unroll
        for (int g = 0; g < 2; ++g) {
#pragma unroll
            for (int ms = 0; ms < 2; ++ms)
#pragma unroll
                for (int r = 0; r < 4; ++r)
                    if (ma[g][ms][r] == 0) s[g][ms][r] = -1.0e30f;
            float mx = fmaxf(fmaxf(fmaxf(s[g][0][0], s[g][0][1]), fmaxf(s[g][0][2], s[g][0][3])),
                             fmaxf(fmaxf(s[g][1][0], s[g][1][1]), fmaxf(s[g][1][2], s[g][1][3])));
            smaxl[g] = mx;
            dmax = fmaxf(dmax, mx - m_run[g]);
        }
        if (!__all(dmax <= 8.0f)) {        // rare after warm-up
#pragma unroll
            for (int g = 0; g < 2; ++g) {
                float mx = smaxl[g];
                mx = fmaxf(mx, __shfl_xor(mx, 16, 64));
                mx = fmaxf(mx, __shfl_xor(mx, 32, 64));
                float mnew = fmaxf(m_run[g], mx);
                float c = exp2f(m_run[g] - mnew);
                m_run[g] = mnew;
                l_part[g] *= c;
#pragma unroll
                for (int ds = 0; ds < 8; ++ds) acc[g][ds] *= c;
            }
        }

#pragma unroll
        for (int g = 0; g < 2; ++g) {
            bf16x4v pbv[2];
#pragma unroll
            for (int ms = 0; ms < 2; ++ms)
#pragma unroll
                for (int r = 0; r < 4; ++r) {
                    float p = exp2f(s[g][ms][r] - m_run[g]);   // p <= 2^8
                    __bf16 pb = (__bf16)p;
                    l_part[g] += (float)pb;    // l matches PV weights exactly
                    pbv[ms][r] = pb;
                }
            const int base = (w * 2 + g) * 1024 + l15 * 64;
#pragma unroll
            for (int ms = 0; ms < 2; ++ms)
                *reinterpret_cast<bf16x4v*>(reinterpret_cast<char*>(p_lds)
                    + base + ms * 32 + lhi * 8) = pbv[ms];
            bf16x8 pa = lds_read16(p_lds, base + lhi * 16);
            __builtin_amdgcn_s_setprio(1);
#pragma unroll
            for (int ds = 0; ds < 8; ++ds)
                acc[g][ds] = __builtin_amdgcn_mfma_f32_16x16x32_bf16(
                    vf[ds], pa, acc[g][ds], 0, 0, 0);
            __builtin_amdgcn_s_setprio(0);
        }
    };

    // ---- pipeline: stage/adj-load(t+1) issued before compute(t); sync per tile
    i32x4 maskA[2][2], maskB[2][2];
    stage(stA, ptbase);
    adjld(maskA, ptbase);
    __syncthreads();

    for (int t = 0; t < ntl; t += 2) {
        stage(stB, ptbase + t + 1);
        adjld(maskB, ptbase + t + 1);
        compute(stA, maskA);
        __syncthreads();
        int t2 = (t + 2 < ntl) ? t + 2 : ntl - 1;
        stage(stA, ptbase + t2);
        adjld(maskA, ptbase + t2);
        compute(stB, maskB);
        __syncthreads();
    }

    // ---- epilogue: deferred cross-lhi l reduction (2 shfls, linear=exact)
#pragma unroll
    for (int g = 0; g < 2; ++g) {
        float rs = l_part[g];
        rs += __shfl_xor(rs, 16, 64);
        rs += __shfl_xor(rs, 32, 64);
        l_part[g] = rs;
    }

    float* op = (sp == 0) ? out : (opart1 + (size_t)(sp - 1) * NR * ND);
#pragma unroll
    for (int g = 0; g < 2; ++g) {
        const size_t rowbase = (bN + q0w + g * 16 + l15) * ND;
#pragma unroll
        for (int ds = 0; ds < 8; ++ds)
            *reinterpret_cast<f32x4*>(op + rowbase + 16 * ds + 4 * lhi) = acc[g][ds];
    }
    if (lhi == 0) {
#pragma unroll
        for (int g = 0; g < 2; ++g) {
            size_t gr = bN + q0w + g * 16 + l15;
            *reinterpret_cast<float2*>(ml + ((size_t)sp * NR + gr) * 2) =
                make_float2(m_run[g], l_part[g]);
        }
    }
}

// ---------------- Kernel 3: merge the KV-splits (m is log2-domain) -------------
__global__ __launch_bounds__(256) void merge_splits(
    float* __restrict__ out, const float* __restrict__ opart1,
    const float* __restrict__ ml, int nsplit)
{
    int idx = blockIdx.x * 256 + threadIdx.x;
    int row = idx >> 5;
    int d4 = (idx & 31) * 4;
    float mmax = ml[(size_t)row * 2];
    for (int sp = 1; sp < nsplit; ++sp)
        mmax = fmaxf(mmax, ml[((size_t)sp * NR + row) * 2]);
    f32x4 o0 = *reinterpret_cast<const f32x4*>(out + (size_t)row * ND + d4);
    float w0 = exp2f(ml[(size_t)row * 2] - mmax);
    float lsum = ml[(size_t)row * 2 + 1] * w0;
    f32x4 acc;
#pragma unroll
    for (int j = 0; j < 4; ++j) acc[j] = o0[j] * w0;
    for (int sp = 1; sp < nsplit; ++sp) {
        float m_s = ml[((size_t)sp * NR + row) * 2];
        float l_s = ml[((size_t)sp * NR + row) * 2 + 1];
        float ws_ = exp2f(m_s - mmax);
        f32x4 os = *reinterpret_cast<const f32x4*>(opart1 + ((size_t)(sp - 1) * NR + row) * ND + d4);
#pragma unroll
        for (int j = 0; j < 4; ++j) acc[j] += os[j] * ws_;
        lsum += l_s * ws_;
    }
    float inv = 1.0f / lsum;
    f32x4 r;
#pragma unroll
    for (int j = 0; j < 4; ++j) r[j] = acc[j] * inv;
    *reinterpret_cast<f32x4*>(out + (size_t)row * ND + d4) = r;
}

extern "C" void kernel_launch(void* const* d_in, const int* in_sizes, int n_in,
                              void* d_out, int out_size, void* d_ws, size_t ws_size,
                              hipStream_t stream) {
    const float* h  = (const float*)d_in[0];
    const int* adj  = (const int*)d_in[1];
    const float* Wq = (const float*)d_in[2];
    const float* bq = (const float*)d_in[3];
    const float* Wk = (const float*)d_in[4];
    const float* bk = (const float*)d_in[5];
    const float* Wv = (const float*)d_in[6];
    const float* bv = (const float*)d_in[7];
    float* out = (float*)d_out;

    unsigned short* qws  = (unsigned short*)d_ws;
    unsigned short* kws  = qws + QKVE;
    unsigned short* vsws = kws + QKVE;
    float* opart1 = (float*)(vsws + QKVE);

    const size_t need4 = 3 * QKVE * 2 + 3 * QKVE * 4 + 4 * (size_t)NR * 2 * 4;
    const int nsplit = (ws_size >= need4) ? 4 : 2;
    float* mlws = opart1 + (size_t)(nsplit - 1) * NR * ND;
    const int ntl = (NN / KVB) / nsplit;                          // 32 or 64

    // 1/(sqrt(128) * ln2): scores land in log2 units -> exp2 softmax
    const float qscale = (float)(0.08838834764831845 / 0.6931471805599453);

    qkv_proj<<<dim3(768), 256, 0, stream>>>(
        h, Wq, bq, Wk, bk, Wv, bv, qws, kws, vsws, qscale);
    attn<<<dim3(32 * 4 * nsplit), 256, 0, stream>>>(
        qws, kws, vsws, adj, out, opart1, mlws, ntl);
    merge_splits<<<dim3(NR * 32 / 256), 256, 0, stream>>>(out, opart1, mlws, nsplit);
}